// Round 11
// baseline (1259.826 us; speedup 1.0000x reference)
//
#include <hip/hip_runtime.h>

typedef unsigned short u16;
typedef unsigned int u32;
typedef __attribute__((ext_vector_type(8))) short bf16x8;
typedef __attribute__((ext_vector_type(4))) float f32x4;

#define T_STEPS 512
#define FEAT 128
#define H1 200
#define G1P 832            // 4 gates x 208 (padded gate stride, 13 tiles/gate)
#define KP 224
#define HB_U16 3584        // one h buffer: 16 rows x 224 cols (bf16)
#define XG_T_BYTES 425984  // 256 * 832 * 2
#define XG_WG_BYTES 6656   // 4 * 832 * 2

// async global->LDS, 16B/lane; LDS dest wave-uniform base (+lane*16 in HW)
#define G2L16(g, lp) __builtin_amdgcn_global_load_lds( \
    (const __attribute__((address_space(1))) void*)(g), \
    (__attribute__((address_space(3))) void*)(lp), 16, 0, 0)

__device__ __forceinline__ u16 f2bf(float x) {
    u32 u = __float_as_uint(x);
    u = (u + 0x7fffu + ((u >> 16) & 1u)) >> 16;
    return (u16)u;
}
__device__ __forceinline__ float bfu2f(u32 u) { return __uint_as_float(u << 16); }

__device__ __forceinline__ float sig2(float x) {
    return __builtin_amdgcn_rcpf(1.f + __builtin_amdgcn_exp2f(-1.442695041f * x));
}
__device__ __forceinline__ float tanh2(float x) {
    return 1.f - 2.f * __builtin_amdgcn_rcpf(1.f + __builtin_amdgcn_exp2f(2.885390082f * x));
}

// ---------------------------------------------------------------------------
// Kernel 1: repack to bf16 MFMA B-fragment order in PADDED column space.
// col' in [0,832): gate g = col'/208, j = col'%208; raw weight row = g*200+j
// (zero for j>=200). whhf: 52 tiles [tile*7+kt][lane][8] (K zero-pad >=200);
// wihf: 52 tiles x 4 kt. b1p: padded bias.
// ---------------------------------------------------------------------------
__global__ void repack_k(const float* __restrict__ wih1, const float* __restrict__ whh1,
                         const float* __restrict__ bih1, const float* __restrict__ bhh1,
                         u16* __restrict__ wihf, u16* __restrict__ whhf, float* __restrict__ b1p) {
    int id = blockIdx.x * 256 + threadIdx.x;
    if (id < G1P) {
        int g = id / 208, j = id - g * 208;
        b1p[id] = (j < H1) ? (bih1[g * H1 + j] + bhh1[g * H1 + j]) : 0.f;
    }
    if (id < 23296) { // 52*7*64 lane-slots for whh
        int l = id & 63, fi = id >> 6;
        int kt = fi % 7, tile = fi / 7;
        int g = tile / 13, jt = tile - g * 13;
        int j = jt * 16 + (l & 15);
        int kb = kt * 32 + (l >> 4) * 8;
        u16 o[8];
#pragma unroll
        for (int jj = 0; jj < 8; ++jj) {
            int k = kb + jj;
            float v = (j < H1 && k < H1) ? whh1[(g * H1 + j) * H1 + k] : 0.f;
            o[jj] = f2bf(v);
        }
        uint4 pk;
        pk.x = (u32)o[0] | ((u32)o[1] << 16);
        pk.y = (u32)o[2] | ((u32)o[3] << 16);
        pk.z = (u32)o[4] | ((u32)o[5] << 16);
        pk.w = (u32)o[6] | ((u32)o[7] << 16);
        *(uint4*)(whhf + (size_t)id * 8) = pk;
    }
    int id2 = id - 23296;
    if (id2 >= 0 && id2 < 13312) { // 52*4*64 lane-slots for wih
        int l = id2 & 63, fi = id2 >> 6;
        int kt = fi & 3, tile = fi >> 2;
        int g = tile / 13, jt = tile - g * 13;
        int j = jt * 16 + (l & 15);
        int kb = kt * 32 + (l >> 4) * 8;
        u16 o[8];
#pragma unroll
        for (int jj = 0; jj < 8; ++jj) {
            int k = kb + jj;
            float v = (j < H1) ? wih1[(g * H1 + j) * FEAT + k] : 0.f;
            o[jj] = f2bf(v);
        }
        uint4 pk;
        pk.x = (u32)o[0] | ((u32)o[1] << 16);
        pk.y = (u32)o[2] | ((u32)o[3] << 16);
        pk.z = (u32)o[4] | ((u32)o[5] << 16);
        pk.w = (u32)o[6] | ((u32)o[7] << 16);
        *(uint4*)(wihf + (size_t)id2 * 8) = pk;
    }
}

// ---------------------------------------------------------------------------
// Kernel 2: xg = X @ W_ih1^T + bias, bf16, natural layout xg[t][b][col' 0..831]
// (r4-r10 verbatim code; padded space comes from the new wihf/b1p mapping)
// ---------------------------------------------------------------------------
__global__ __launch_bounds__(256, 1) void xg_gemm(const float* __restrict__ X,
                                                  const u16* __restrict__ wihf,
                                                  const float* __restrict__ b1p,
                                                  u16* __restrict__ xg) {
    __shared__ u16 xs[64 * 128];
    int tid = threadIdx.x, wg = blockIdx.x;
    int l = tid & 63, wv = tid >> 6;
    int arow = l & 15, khi = l >> 4;

    const float4* Xv = (const float4*)(X + (size_t)wg * 64 * 128);
#pragma unroll
    for (int i = 0; i < 8; ++i) {
        int idx = tid + i * 256;
        float4 v = Xv[idx];
        int row = idx >> 5;
        int col = (idx & 31) * 4;
        uint2 pk;
        pk.x = (u32)f2bf(v.x) | ((u32)f2bf(v.y) << 16);
        pk.y = (u32)f2bf(v.z) | ((u32)f2bf(v.w) << 16);
        int byteo = (row * 256 + col * 2) ^ ((row & 7) << 4);
        *(uint2*)((char*)xs + byteo) = pk;
    }
    __syncthreads();

    f32x4 acc[4][13];
#pragma unroll
    for (int mt = 0; mt < 4; ++mt)
#pragma unroll
        for (int nt = 0; nt < 13; ++nt) acc[mt][nt] = (f32x4){0.f, 0.f, 0.f, 0.f};

#pragma unroll
    for (int kt = 0; kt < 4; ++kt) {
        bf16x8 wfr[13];
#pragma unroll
        for (int nt = 0; nt < 13; ++nt) {
            int ntg = wv * 13 + nt;
            wfr[nt] = *(const bf16x8*)(wihf + ((size_t)(ntg * 4 + kt) * 64 + l) * 8);
        }
#pragma unroll
        for (int mt = 0; mt < 4; ++mt) {
            int row = mt * 16 + arow;
            int byteo = (row * 256 + kt * 64 + khi * 16) ^ ((row & 7) << 4);
            bf16x8 a = *(const bf16x8*)((const char*)xs + byteo);
#pragma unroll
            for (int nt = 0; nt < 13; ++nt)
                acc[mt][nt] = __builtin_amdgcn_mfma_f32_16x16x32_bf16(a, wfr[nt], acc[mt][nt], 0, 0, 0);
        }
    }

    int t = wg >> 2;
#pragma unroll
    for (int nt = 0; nt < 13; ++nt) {
        int ntg = wv * 13 + nt;
        int colg = ntg * 16 + arow;
        float bias = b1p[colg];
#pragma unroll
        for (int mt = 0; mt < 4; ++mt) {
#pragma unroll
            for (int r = 0; r < 4; ++r) {
                int bg = (wg & 3) * 64 + mt * 16 + khi * 4 + r;
                xg[((size_t)t * 256 + bg) * G1P + colg] = f2bf(acc[mt][nt][r] + bias);
            }
        }
    }
}

// ---------------------------------------------------------------------------
// Kernel 3: persistent fused 2-layer LSTM. 64 WGs x 512 threads (8 waves).
// Gate-column groups {T, T+13, T+26, T+39} = (i,f,g,o) of same hidden cols ->
// elementwise ENTIRELY IN-REGISTER on lanes 0-15 (no gbuf, no LDS roundtrip).
// hbuf double-buffered -> ONE barrier/step. Heavy waves: 5 reg tiles + 3 LDS
// tiles; light waves 4 reg tiles (+staging / layer-2). All MFMA intrinsic.
// ---------------------------------------------------------------------------
#define LDHB(KT) (*(const bf16x8*)(hbr + ((arow * 448 + (KT) * 64 + khi * 16) ^ ((arow & 7) << 4))))
#define LDSW(J, KT) (*(const bf16x8*)((const char*)wlds + (size_t)(slot0 + (J)) * 7168 + (KT) * 1024 + l * 16))

template<int NREG, int NLDS, int NST, bool L2O>
__device__ __forceinline__ void lstm_body(
    int TgA, int TgB, int slot0, int stgoff, int wv, int l, int mw,
    const u16* __restrict__ xg, const u16* __restrict__ whhf,
    const float* __restrict__ w_ih2, const float* __restrict__ w_hh2,
    const float* __restrict__ b_ih2, const float* __restrict__ b_hh2,
    float* __restrict__ out, u16* hbuf, u16* xgs, const u16* wlds)
{
    const int arow = l & 15, khi = l >> 4;
    const f32x4 fz = {0.f, 0.f, 0.f, 0.f};

    // reg-resident W_hh tiles: {TgA, TgA+13, TgA+26, TgA+39} [, TgB]
    bf16x8 wf[NREG][7];
#pragma unroll
    for (int nt = 0; nt < NREG; ++nt) {
        int tile = (nt < 4) ? TgA + nt * 13 : TgB;
#pragma unroll
        for (int kt = 0; kt < 7; ++kt)
            wf[nt][kt] = *(const bf16x8*)(whhf + ((size_t)(tile * 7 + kt) * 64 + l) * 8);
    }

    // layer-2 state (wave 7 only) — r9/r10 verbatim
    bf16x8 wf2[7];
    float wh[4][3], b2l[4], h2p[4], c2[4];
    f32x4 acc2 = fz;
    if constexpr (L2O) {
#pragma unroll
        for (int kt = 0; kt < 7; ++kt) {
            u16 o[8];
#pragma unroll
            for (int jj = 0; jj < 8; ++jj) {
                int k = kt * 32 + khi * 8 + jj;
                o[jj] = (arow < 12 && k < H1) ? f2bf(w_ih2[arow * H1 + k]) : (u16)0;
            }
            uint4 pk;
            pk.x = (u32)o[0] | ((u32)o[1] << 16);
            pk.y = (u32)o[2] | ((u32)o[3] << 16);
            pk.z = (u32)o[4] | ((u32)o[5] << 16);
            pk.w = (u32)o[6] | ((u32)o[7] << 16);
            wf2[kt] = *(bf16x8*)&pk;
        }
        int hs = (l < 3) ? l : 0;
#pragma unroll
        for (int g = 0; g < 4; ++g) {
#pragma unroll
            for (int q = 0; q < 3; ++q) wh[g][q] = w_hh2[(g * 3 + hs) * 3 + q];
            b2l[g] = b_ih2[g * 3 + hs] + b_hh2[g * 3 + hs];
        }
#pragma unroll
        for (int r = 0; r < 4; ++r) { h2p[r] = 0.f; c2[r] = 0.f; }
    }

    float cA[4] = {0.f, 0.f, 0.f, 0.f};
    float cB[4] = {0.f, 0.f, 0.f, 0.f};

    auto L2EW = [&](int tout) {
        int hs = (l < 3) ? l : 0;
#pragma unroll
        for (int r = 0; r < 4; ++r) {
            float pi = __shfl(acc2[r], hs);
            float pf = __shfl(acc2[r], 3 + hs);
            float pg = __shfl(acc2[r], 6 + hs);
            float po = __shfl(acc2[r], 9 + hs);
            float hq0 = __shfl(h2p[r], 0);
            float hq1 = __shfl(h2p[r], 1);
            float hq2 = __shfl(h2p[r], 2);
            pi += b2l[0] + wh[0][0] * hq0 + wh[0][1] * hq1 + wh[0][2] * hq2;
            pf += b2l[1] + wh[1][0] * hq0 + wh[1][1] * hq1 + wh[1][2] * hq2;
            pg += b2l[2] + wh[2][0] * hq0 + wh[2][1] * hq1 + wh[2][2] * hq2;
            po += b2l[3] + wh[3][0] * hq0 + wh[3][1] * hq1 + wh[3][2] * hq2;
            float gi = sig2(pi), gf = sig2(pf), gg = tanh2(pg), go = sig2(po);
            c2[r] = gf * c2[r] + gi * gg;
            h2p[r] = go * tanh2(c2[r]);
            if (l < 3) out[(size_t)tout * 768 + (mw * 4 + r) * 3 + l] = h2p[r];
        }
    };

    // in-register elementwise for one gate-column group (lanes 0-15 only)
    auto EWG = [&](int Tg, const f32x4& ia, const f32x4& fa, const f32x4& ga,
                   const f32x4& oa, float* cr, const u16* xr, char* hbw) {
        int cb = Tg * 16 + l; // = j (hidden col in padded [0,208) space)
#pragma unroll
        for (int r = 0; r < 4; ++r) {
            float pi = ia[r] + bfu2f(xr[r * 832 + cb]);
            float pf = fa[r] + bfu2f(xr[r * 832 + 208 + cb]);
            float pg = ga[r] + bfu2f(xr[r * 832 + 416 + cb]);
            float po = oa[r] + bfu2f(xr[r * 832 + 624 + cb]);
            float gi = sig2(pi), gf = sig2(pf), gg = tanh2(pg), go = sig2(po);
            cr[r] = gf * cr[r] + gi * gg;
            float h = go * tanh2(cr[r]);
            *(u16*)(hbw + ((r * 448 + cb * 2) ^ (r << 4))) = f2bf(h);
        }
    };

    // prologue: stage xg(t=0), drain, full-WG barrier
    const char* sp = (const char*)xg + (size_t)mw * XG_WG_BYTES + stgoff;
    if constexpr (NST > 0) {
        char* d = (char*)xgs + stgoff;
        G2L16(sp + (size_t)l * 16, d);
        G2L16(sp + 1024 + (size_t)l * 16, d + 1024);
        if constexpr (NST == 3) { if (l < 32) G2L16(sp + 2048 + (size_t)l * 16, d + 2048); }
        sp += XG_T_BYTES;
        asm volatile("s_waitcnt vmcnt(0)" ::: "memory");
    }
    __builtin_amdgcn_s_barrier();

    for (int t = 0; t < T_STEPS; ++t) {
        const char* hbr = (const char*)(hbuf + (t & 1) * HB_U16);
        char* hbw = (char*)(hbuf + ((t + 1) & 1) * HB_U16);
        const u16* xr = xgs + (t & 1) * 3328;

        bf16x8 ha0 = LDHB(0), ha1 = LDHB(1), ha2 = LDHB(2);
        bf16x8 wb0[NLDS ? NLDS : 1], wb1[NLDS ? NLDS : 1];
        if constexpr (NLDS > 0) {
#pragma unroll
            for (int j = 0; j < NLDS; ++j) wb0[j] = LDSW(j, 0);
        }

        if constexpr (NST > 0) { // stage xg(t+1); stays in flight across barrier
            char* d = (char*)xgs + ((t + 1) & 1) * 6656 + stgoff;
            G2L16(sp + (size_t)l * 16, d);
            G2L16(sp + 1024 + (size_t)l * 16, d + 1024);
            if constexpr (NST == 3) { if (l < 32) G2L16(sp + 2048 + (size_t)l * 16, d + 2048); }
            sp += XG_T_BYTES;
        }
        if constexpr (L2O) {
            if (t >= 2) L2EW(t - 2); // consumes prev-iteration acc2
        }

        f32x4 acc[NREG], accL[NLDS ? NLDS : 1];
        // kt = 0
#pragma unroll
        for (int nt = 0; nt < NREG; ++nt)
            acc[nt] = __builtin_amdgcn_mfma_f32_16x16x32_bf16(ha0, wf[nt][0], fz, 0, 0, 0);
        if constexpr (NLDS > 0) {
#pragma unroll
            for (int j = 0; j < NLDS; ++j) accL[j] = __builtin_amdgcn_mfma_f32_16x16x32_bf16(ha0, wb0[j], fz, 0, 0, 0);
#pragma unroll
            for (int j = 0; j < NLDS; ++j) wb1[j] = LDSW(j, 1);
        }
        if constexpr (L2O) acc2 = __builtin_amdgcn_mfma_f32_16x16x32_bf16(ha0, wf2[0], fz, 0, 0, 0);
        ha0 = LDHB(3);
        // kt = 1
#pragma unroll
        for (int nt = 0; nt < NREG; ++nt)
            acc[nt] = __builtin_amdgcn_mfma_f32_16x16x32_bf16(ha1, wf[nt][1], acc[nt], 0, 0, 0);
        if constexpr (NLDS > 0) {
#pragma unroll
            for (int j = 0; j < NLDS; ++j) accL[j] = __builtin_amdgcn_mfma_f32_16x16x32_bf16(ha1, wb1[j], accL[j], 0, 0, 0);
#pragma unroll
            for (int j = 0; j < NLDS; ++j) wb0[j] = LDSW(j, 2);
        }
        if constexpr (L2O) acc2 = __builtin_amdgcn_mfma_f32_16x16x32_bf16(ha1, wf2[1], acc2, 0, 0, 0);
        ha1 = LDHB(4);
        // kt = 2
#pragma unroll
        for (int nt = 0; nt < NREG; ++nt)
            acc[nt] = __builtin_amdgcn_mfma_f32_16x16x32_bf16(ha2, wf[nt][2], acc[nt], 0, 0, 0);
        if constexpr (NLDS > 0) {
#pragma unroll
            for (int j = 0; j < NLDS; ++j) accL[j] = __builtin_amdgcn_mfma_f32_16x16x32_bf16(ha2, wb0[j], accL[j], 0, 0, 0);
#pragma unroll
            for (int j = 0; j < NLDS; ++j) wb1[j] = LDSW(j, 3);
        }
        if constexpr (L2O) acc2 = __builtin_amdgcn_mfma_f32_16x16x32_bf16(ha2, wf2[2], acc2, 0, 0, 0);
        ha2 = LDHB(5);
        // kt = 3
#pragma unroll
        for (int nt = 0; nt < NREG; ++nt)
            acc[nt] = __builtin_amdgcn_mfma_f32_16x16x32_bf16(ha0, wf[nt][3], acc[nt], 0, 0, 0);
        if constexpr (NLDS > 0) {
#pragma unroll
            for (int j = 0; j < NLDS; ++j) accL[j] = __builtin_amdgcn_mfma_f32_16x16x32_bf16(ha0, wb1[j], accL[j], 0, 0, 0);
#pragma unroll
            for (int j = 0; j < NLDS; ++j) wb0[j] = LDSW(j, 4);
        }
        if constexpr (L2O) acc2 = __builtin_amdgcn_mfma_f32_16x16x32_bf16(ha0, wf2[3], acc2, 0, 0, 0);
        ha0 = LDHB(6);
        // kt = 4
#pragma unroll
        for (int nt = 0; nt < NREG; ++nt)
            acc[nt] = __builtin_amdgcn_mfma_f32_16x16x32_bf16(ha1, wf[nt][4], acc[nt], 0, 0, 0);
        if constexpr (NLDS > 0) {
#pragma unroll
            for (int j = 0; j < NLDS; ++j) accL[j] = __builtin_amdgcn_mfma_f32_16x16x32_bf16(ha1, wb0[j], accL[j], 0, 0, 0);
#pragma unroll
            for (int j = 0; j < NLDS; ++j) wb1[j] = LDSW(j, 5);
        }
        if constexpr (L2O) acc2 = __builtin_amdgcn_mfma_f32_16x16x32_bf16(ha1, wf2[4], acc2, 0, 0, 0);
        // kt = 5
#pragma unroll
        for (int nt = 0; nt < NREG; ++nt)
            acc[nt] = __builtin_amdgcn_mfma_f32_16x16x32_bf16(ha2, wf[nt][5], acc[nt], 0, 0, 0);
        if constexpr (NLDS > 0) {
#pragma unroll
            for (int j = 0; j < NLDS; ++j) accL[j] = __builtin_amdgcn_mfma_f32_16x16x32_bf16(ha2, wb1[j], accL[j], 0, 0, 0);
#pragma unroll
            for (int j = 0; j < NLDS; ++j) wb0[j] = LDSW(j, 6);
        }
        if constexpr (L2O) acc2 = __builtin_amdgcn_mfma_f32_16x16x32_bf16(ha2, wf2[5], acc2, 0, 0, 0);
        // kt = 6
#pragma unroll
        for (int nt = 0; nt < NREG; ++nt)
            acc[nt] = __builtin_amdgcn_mfma_f32_16x16x32_bf16(ha0, wf[nt][6], acc[nt], 0, 0, 0);
        if constexpr (NLDS > 0) {
#pragma unroll
            for (int j = 0; j < NLDS; ++j) accL[j] = __builtin_amdgcn_mfma_f32_16x16x32_bf16(ha0, wb0[j], accL[j], 0, 0, 0);
        }
        if constexpr (L2O) acc2 = __builtin_amdgcn_mfma_f32_16x16x32_bf16(ha0, wf2[6], acc2, 0, 0, 0);

        // in-register elementwise (lanes 0-15 hold all 4 batch rows)
        if (l < 16) {
            EWG(TgA, acc[0], acc[1], acc[2], acc[3], cA, xr, hbw);
            if constexpr (NREG == 5)
                EWG(TgB, acc[4], accL[0], accL[1], accL[2], cB, xr, hbw);
        }

        if constexpr (NST == 2) asm volatile("s_waitcnt vmcnt(2)" ::: "memory");
        if constexpr (NST == 3) asm volatile("s_waitcnt vmcnt(3)" ::: "memory");
        asm volatile("s_waitcnt lgkmcnt(0)" ::: "memory");
        __builtin_amdgcn_s_barrier(); // single barrier per step
    }

    asm volatile("s_waitcnt vmcnt(0)" ::: "memory"); // drain dangling t=512 stage

    // epilogue (wave 7): layer-2 for steps 510 and 511
    if constexpr (L2O) {
        L2EW(510);
        const char* hbr = (const char*)(hbuf + (T_STEPS & 1) * HB_U16); // h(511)
        bf16x8 he = LDHB(0);
        acc2 = __builtin_amdgcn_mfma_f32_16x16x32_bf16(he, wf2[0], fz, 0, 0, 0);
#pragma unroll
        for (int kt = 1; kt < 7; ++kt) {
            he = LDHB(kt);
            acc2 = __builtin_amdgcn_mfma_f32_16x16x32_bf16(he, wf2[kt], acc2, 0, 0, 0);
        }
        L2EW(511);
    }
}

__global__ __launch_bounds__(512, 2)
void lstm_main(const u16* __restrict__ xg,
               const u16* __restrict__ whhf,
               const float* __restrict__ w_ih2,
               const float* __restrict__ w_hh2,
               const float* __restrict__ b_ih2,
               const float* __restrict__ b_hh2,
               float* __restrict__ out) {
    __shared__ __align__(16) u16 hbuf[2 * HB_U16];   //  14336 B, dbuf'd swizzled h
    __shared__ __align__(16) u16 xgs[2 * 3328];      //  13312 B, staged xg (dbuf)
    __shared__ __align__(16) u16 wlds[15 * 3584];    // 107520 B, LDS B-frag tiles
    // total 135,168 B -> 1 WG/CU, 8 waves = 2 waves/SIMD

    int tid = threadIdx.x, mw = blockIdx.x;
    int l = tid & 63, wv = tid >> 6;

    for (int i = tid; i < 2 * HB_U16; i += 512) hbuf[i] = 0;
    // preload LDS weight tiles: slot s (wave s/3) holds tile (2*(s/3)+1)+13*((s%3)+1)
    for (int i = tid; i < 15 * 448; i += 512) {
        int s = i / 448, off = i - s * 448;
        int Tsrc = (2 * (s / 3) + 1) + 13 * ((s % 3) + 1);
        ((uint4*)wlds)[(size_t)s * 448 + off] = ((const uint4*)whhf)[(size_t)Tsrc * 448 + off];
    }
    __syncthreads();

    // heavy waves 0-4: Tg pairs {2w,2w+1}, 5 reg + 3 LDS tiles;
    // w5,w6: Tg 10,11 + staging; w7: Tg 12 + staging + layer-2
    if (wv == 0)
        lstm_body<5, 3, 0, false>(0, 1, 0, 0, 0, l, mw, xg, whhf, w_ih2, w_hh2, b_ih2, b_hh2, out, hbuf, xgs, wlds);
    else if (wv == 1)
        lstm_body<5, 3, 0, false>(2, 3, 3, 0, 1, l, mw, xg, whhf, w_ih2, w_hh2, b_ih2, b_hh2, out, hbuf, xgs, wlds);
    else if (wv == 2)
        lstm_body<5, 3, 0, false>(4, 5, 6, 0, 2, l, mw, xg, whhf, w_ih2, w_hh2, b_ih2, b_hh2, out, hbuf, xgs, wlds);
    else if (wv == 3)
        lstm_body<5, 3, 0, false>(6, 7, 9, 0, 3, l, mw, xg, whhf, w_ih2, w_hh2, b_ih2, b_hh2, out, hbuf, xgs, wlds);
    else if (wv == 4)
        lstm_body<5, 3, 0, false>(8, 9, 12, 0, 4, l, mw, xg, whhf, w_ih2, w_hh2, b_ih2, b_hh2, out, hbuf, xgs, wlds);
    else if (wv == 5)
        lstm_body<4, 0, 2, false>(10, 0, 0, 0, 5, l, mw, xg, whhf, w_ih2, w_hh2, b_ih2, b_hh2, out, hbuf, xgs, wlds);
    else if (wv == 6)
        lstm_body<4, 0, 2, false>(11, 0, 0, 2048, 6, l, mw, xg, whhf, w_ih2, w_hh2, b_ih2, b_hh2, out, hbuf, xgs, wlds);
    else
        lstm_body<4, 0, 3, true>(12, 0, 0, 4096, 7, l, mw, xg, whhf, w_ih2, w_hh2, b_ih2, b_hh2, out, hbuf, xgs, wlds);
}

extern "C" void kernel_launch(void* const* d_in, const int* in_sizes, int n_in,
                              void* d_out, int out_size, void* d_ws, size_t ws_size,
                              hipStream_t stream) {
    const float* X = (const float*)d_in[0];
    const float* w_ih1 = (const float*)d_in[1];
    const float* w_hh1 = (const float*)d_in[2];
    const float* b_ih1 = (const float*)d_in[3];
    const float* b_hh1 = (const float*)d_in[4];
    const float* w_ih2 = (const float*)d_in[5];
    const float* w_hh2 = (const float*)d_in[6];
    const float* b_ih2 = (const float*)d_in[7];
    const float* b_hh2 = (const float*)d_in[8];
    float* out = (float*)d_out;

    char* ws = (char*)d_ws;
    size_t off = 0;
    u16* xg = (u16*)(ws + off);
    off += (size_t)512 * 256 * G1P * 2; // 218,103,808 B
    u16* whhf = (u16*)(ws + off);
    off += (size_t)23296 * 8 * 2; // 372,736 B (also absorbs t=512 stage overread)
    u16* wihf = (u16*)(ws + off);
    off += (size_t)13312 * 8 * 2; // 212,992 B
    float* b1p = (float*)(ws + off);
    off += G1P * 4;
    if (ws_size < off) return; // insufficient workspace -> visible failure

    repack_k<<<143, 256, 0, stream>>>(w_ih1, w_hh1, b_ih1, b_hh1, wihf, whhf, b1p);
    xg_gemm<<<2048, 256, 0, stream>>>(X, wihf, b1p, xg);
    lstm_main<<<64, 512, 0, stream>>>(xg, whhf, w_ih2, w_hh2, b_ih2, b_hh2, out);
}